// Round 4
// baseline (574.122 us; speedup 1.0000x reference)
//
#include <hip/hip_runtime.h>
#include <stdint.h>
#include <stddef.h>

// AnchorAttention on MI355X (gfx950). FP32 I/O, fp16 MFMA internally.
// Round 4: register-staged double-buffered GEMM K-loop (prefetch survives the
// barrier), fused fp32->fp16 convert into staging, XCD-locality block remap.

typedef _Float16 v8hf __attribute__((ext_vector_type(8)));
typedef float    f32x4 __attribute__((ext_vector_type(4)));

#define ATT_SCALE 0.125f   // 1/sqrt(64)
#define LOG2E     1.44269504088896340736f

__device__ __forceinline__ void async16(const void* g, void* l) {
  __builtin_amdgcn_global_load_lds(
      (const __attribute__((address_space(1))) void*)g,
      (__attribute__((address_space(3))) void*)l,
      16, 0, 0);
}

// ---------------------------------------------------------------------------
// Fused transpose+convert for all 5 weight matrices (1024x1024 each):
//   dst[z][c*1024 + r] = (fp16)src[z][r*1024 + c]
// ---------------------------------------------------------------------------
struct TPArgs { const float* src[5]; _Float16* dst[5]; };

__global__ __launch_bounds__(256) void transpose5_k(TPArgs a) {
  __shared__ _Float16 t[32][33];
  const int z = blockIdx.z;
  const float* __restrict__ src = a.src[z];
  _Float16* __restrict__ dst = a.dst[z];
  const int bx = blockIdx.x * 32, by = blockIdx.y * 32;
  const int x = threadIdx.x;
  for (int yy = threadIdx.y; yy < 32; yy += 8)
    t[yy][x] = (_Float16)src[(size_t)(by + yy) * 1024 + bx + x];
  __syncthreads();
  for (int yy = threadIdx.y; yy < 32; yy += 8)
    dst[(size_t)(bx + yy) * 1024 + by + x] = t[x][yy];
}

// ---------------------------------------------------------------------------
// GEMM: C[m,n] = sum_k A[gRow(m),k] * Bt[n,k] + bias[n]
// 256 thr = 4 waves, 128x128 tile, BK=32.
// Register-staged pipeline: loads for tile k+1 issue before tile k's barriers,
// ds_write_b128 into XOR-swizzled LDS (blk ^= (row>>1)&3), fragments via
// ds_read_b128 (conflict-free). A dtype templated: fp32 A converts at staging.
// ---------------------------------------------------------------------------
template <typename AT, typename OutT>
__global__ __launch_bounds__(256) void gemm128(
    const AT* __restrict__ A, const _Float16* __restrict__ Bt,
    const float* __restrict__ bias0, const float* __restrict__ bias1,
    const float* __restrict__ bias2,
    OutT* __restrict__ out0, _Float16* __restrict__ out1, _Float16* __restrict__ out2,
    int rowsPerBatch, int rowStart, int mode)
{
  constexpr bool AF32 = (sizeof(AT) == 4);
  __shared__ __attribute__((aligned(16))) _Float16 As[128 * 32];
  __shared__ __attribute__((aligned(16))) _Float16 Bs[128 * 32];

  const int tid  = threadIdx.x;
  const int wave = tid >> 6, lane = tid & 63;
  const int quad = lane >> 4, l16 = lane & 15;
  const int wr = wave >> 1, wc = wave & 1;

  // XCD-locality remap: lin%8 -> XCD (dispatch heuristic). Each XCD gets a
  // contiguous by-range covering all bx: A panels fetched once, Bt hot in L2.
  const int gx = gridDim.x;
  const int lin = blockIdx.y * gx + blockIdx.x;
  const int x8 = lin & 7, j = lin >> 3;
  const int bx = j % gx;
  const int by = x8 * (gridDim.y >> 3) + j / gx;

  const int c0 = wave * 2, c1 = c0 + 1;   // LDS chunks: 16 rows x 32 k = 1 KB
  const int srow = lane >> 2;
  const int skol = (((lane & 3) ^ ((lane >> 3) & 3)) * 8);  // swizzled k-col

  auto gRowOf = [&](int m) -> int {
    int b = m / rowsPerBatch;
    int r = m - b * rowsPerBatch;
    return b * 4096 + rowStart + r;
  };

  const AT* aS0 = A + (size_t)gRowOf(by * 128 + c0 * 16 + srow) * 1024 + skol;
  const AT* aS1 = A + (size_t)gRowOf(by * 128 + c1 * 16 + srow) * 1024 + skol;
  const _Float16* bS0 = Bt + (size_t)(bx * 128 + c0 * 16 + srow) * 1024 + skol;
  const _Float16* bS1 = Bt + (size_t)(bx * 128 + c1 * 16 + srow) * 1024 + skol;
  _Float16* aW0 = As + c0 * 512 + lane * 8;
  _Float16* aW1 = As + c1 * 512 + lane * 8;
  _Float16* bW0 = Bs + c0 * 512 + lane * 8;
  _Float16* bW1 = Bs + c1 * 512 + lane * 8;

  // fragment-read swizzle: (row>>1)&3 = (l16>>1)&3 for 16-aligned row bases
  const int fblk = (quad ^ ((l16 >> 1) & 3)) * 8;

  float4 ra[2][4];   // fp32: [lo0,hi0,lo1,hi1]; fp16: [0]=chunk0,[1]=chunk1
  float4 rb[2][2];

  auto loadTile = [&](int k0, int b) {
    if constexpr (AF32) {
      ra[b][0] = *(const float4*)(aS0 + k0);
      ra[b][1] = *(const float4*)(aS0 + k0 + 4);
      ra[b][2] = *(const float4*)(aS1 + k0);
      ra[b][3] = *(const float4*)(aS1 + k0 + 4);
    } else {
      ra[b][0] = *(const float4*)(aS0 + k0);
      ra[b][1] = *(const float4*)(aS1 + k0);
    }
    rb[b][0] = *(const float4*)(bS0 + k0);
    rb[b][1] = *(const float4*)(bS1 + k0);
  };
  auto cvtStore = [&](_Float16* dst, float4 lo, float4 hi) {
    v8hf o;
    o[0] = (_Float16)lo.x; o[1] = (_Float16)lo.y; o[2] = (_Float16)lo.z; o[3] = (_Float16)lo.w;
    o[4] = (_Float16)hi.x; o[5] = (_Float16)hi.y; o[6] = (_Float16)hi.z; o[7] = (_Float16)hi.w;
    *(v8hf*)dst = o;
  };
  auto storeTile = [&](int b) {
    if constexpr (AF32) {
      cvtStore(aW0, ra[b][0], ra[b][1]);
      cvtStore(aW1, ra[b][2], ra[b][3]);
    } else {
      *(float4*)aW0 = ra[b][0];
      *(float4*)aW1 = ra[b][1];
    }
    *(float4*)bW0 = rb[b][0];
    *(float4*)bW1 = rb[b][1];
  };

  f32x4 acc[4][4];
  #pragma unroll
  for (int i = 0; i < 4; i++)
    #pragma unroll
    for (int jj = 0; jj < 4; jj++)
      acc[i][jj] = f32x4{0.f, 0.f, 0.f, 0.f};

  loadTile(0, 0);
  #pragma unroll 2
  for (int k0 = 0; k0 < 1024; k0 += 32) {
    const int cur = (k0 >> 5) & 1;
    if (k0 + 32 < 1024) loadTile(k0 + 32, cur ^ 1);   // prefetch: stays in flight
    __syncthreads();          // prev tile's ds_reads complete
    storeTile(cur);           // vmcnt wait only on cur's (old) loads
    __syncthreads();          // tile visible

    v8hf af[4], bfr[4];
    #pragma unroll
    for (int mt = 0; mt < 4; mt++)
      af[mt] = *(const v8hf*)(As + (wr * 64 + mt * 16 + l16) * 32 + fblk);
    #pragma unroll
    for (int nt = 0; nt < 4; nt++)
      bfr[nt] = *(const v8hf*)(Bs + (wc * 64 + nt * 16 + l16) * 32 + fblk);
    #pragma unroll
    for (int mt = 0; mt < 4; mt++)
      #pragma unroll
      for (int nt = 0; nt < 4; nt++)
        acc[mt][nt] = __builtin_amdgcn_mfma_f32_16x16x32_f16(af[mt], bfr[nt], acc[mt][nt], 0, 0, 0);
  }

  // epilogue: C/D layout col=lane&15, row=quad*4+reg
  const int colBase = bx * 128 + wc * 64;
  const int rowBase = by * 128 + wr * 64;
  #pragma unroll
  for (int mt = 0; mt < 4; mt++) {
    #pragma unroll
    for (int r = 0; r < 4; r++) {
      int m = rowBase + mt * 16 + quad * 4 + r;
      int b = m / rowsPerBatch;
      int rr = m - b * rowsPerBatch;
      #pragma unroll
      for (int nt = 0; nt < 4; nt++) {
        int col = colBase + nt * 16 + l16;
        float v = acc[mt][nt][r];
        if (mode == 0) {
          v += bias0[col];
          out0[(size_t)(b * 4096 + rowStart + rr) * 1024 + col] = (OutT)v;
        } else {
          if (col < 1024) {
            v += bias0[col];
            out0[(size_t)(b * 4096 + rr) * 1024 + col] = (OutT)v;
          } else if (col < 2048) {
            int c2 = col - 1024;
            v += bias1[c2];
            out1[(size_t)(b * 256 + rr) * 1024 + c2] = (_Float16)v;
          } else {
            int c2 = col - 2048;  // vt[(b*16+h)*64+d][key]
            v += bias2[c2];
            out2[(size_t)((b * 16 + (c2 >> 6)) * 64 + (c2 & 63)) * 256 + rr] = (_Float16)v;
          }
        }
      }
    }
  }
}

// ---------------------------------------------------------------------------
// Fused attention: one block = (b, h, 64-query tile). K=256 anchors.
// LDS swizzle (Gray): 16B block blk at row r stored at blk ^ ((r^(r>>1))&7).
// ---------------------------------------------------------------------------
__global__ __launch_bounds__(256) void attn_kernel(
    const _Float16* __restrict__ q, const _Float16* __restrict__ k,
    const _Float16* __restrict__ vt, _Float16* __restrict__ ctx)
{
  __shared__ __attribute__((aligned(16))) _Float16 KP[256 * 64];  // K tile, then P
  __shared__ __attribute__((aligned(16))) _Float16 Vs[64 * 256];  // V^T (d x key)

  const int tid  = threadIdx.x;
  const int wave = tid >> 6, lane = tid & 63;
  const int quad = lane >> 4, l16 = lane & 15;
  const int bid = blockIdx.x;
  const int qt = bid & 63, h = (bid >> 6) & 15, b = bid >> 10;

  const int fq = (l16 ^ (l16 >> 1)) & 7;

  // stage K head tile (256x64 fp16 = 32 KB), swizzled source
  const _Float16* kbase = k + (size_t)b * 256 * 1024 + h * 64;
  {
    const int s = lane >> 3;
    const int p = lane & 7;
    #pragma unroll
    for (int i = 0; i < 8; i++) {
      int c = wave * 8 + i;
      int row = c * 8 + s;
      int f = (row ^ (row >> 1)) & 7;
      int dblk = p ^ f;
      async16(kbase + (size_t)row * 1024 + dblk * 8, KP + c * 512);
    }
  }

  // Q A-fragments straight from global
  const int qrow = qt * 64 + wave * 16 + l16;
  const _Float16* qbase = q + (size_t)(b * 4096 + qrow) * 1024 + h * 64 + quad * 8;
  v8hf a0 = *(const v8hf*)(qbase);
  v8hf a1 = *(const v8hf*)(qbase + 32);

  f32x4 s[16];
  #pragma unroll
  for (int t = 0; t < 16; t++) s[t] = f32x4{0.f, 0.f, 0.f, 0.f};

  __syncthreads();

  #pragma unroll
  for (int t = 0; t < 16; t++) {
    const _Float16* rbase = KP + (t * 16 + l16) * 64;
    int pb0 = (quad ^ fq) * 8;
    v8hf b0 = *(const v8hf*)(rbase + pb0);
    v8hf b1 = *(const v8hf*)(rbase + (pb0 ^ 32));
    s[t] = __builtin_amdgcn_mfma_f32_16x16x32_f16(a0, b0, s[t], 0, 0, 0);
    s[t] = __builtin_amdgcn_mfma_f32_16x16x32_f16(a1, b1, s[t], 0, 0, 0);
  }

  // softmax: lane (quad,l16) holds S[row=quad*4+r][key=t*16+l16]
  const float ce = ATT_SCALE * LOG2E;
  float inv[4];
  #pragma unroll
  for (int r = 0; r < 4; r++) {
    float m = s[0][r];
    #pragma unroll
    for (int t = 1; t < 16; t++) m = fmaxf(m, s[t][r]);
    m = fmaxf(m, __shfl_xor(m, 1));
    m = fmaxf(m, __shfl_xor(m, 2));
    m = fmaxf(m, __shfl_xor(m, 4));
    m = fmaxf(m, __shfl_xor(m, 8));
    float sum = 0.f;
    #pragma unroll
    for (int t = 0; t < 16; t++) {
      float e = exp2f((s[t][r] - m) * ce);
      s[t][r] = e;
      sum += e;
    }
    sum += __shfl_xor(sum, 1);
    sum += __shfl_xor(sum, 2);
    sum += __shfl_xor(sum, 4);
    sum += __shfl_xor(sum, 8);
    inv[r] = 1.0f / sum;
  }

  __syncthreads();  // all waves done reading K -> safe to overwrite with P

  // stage V^T head tile (64 d x 256 keys), swizzled source
  const _Float16* vbase = vt + (size_t)(b * 16 + h) * 16384;
  {
    const int p = lane & 31;
    #pragma unroll
    for (int i = 0; i < 8; i++) {
      int c = wave * 8 + i;
      int d = c * 2 + (lane >> 5);
      int f = (d ^ (d >> 1)) & 7;
      int kblk = p ^ f;
      async16(vbase + d * 256 + kblk * 8, Vs + c * 512);
    }
  }

  // write P into KP as P[64][256], swizzled
  #pragma unroll
  for (int r = 0; r < 4; r++) {
    int qr = wave * 16 + quad * 4 + r;
    int fp = (qr ^ (qr >> 1)) & 7;
    _Float16* prow = KP + qr * 256;
    #pragma unroll
    for (int t = 0; t < 16; t++) {
      int key = t * 16 + l16;
      prow[(((key >> 3) ^ fp) * 8) + (key & 7)] = (_Float16)(s[t][r] * inv[r]);
    }
  }

  __syncthreads();

  // ctx = P V
  f32x4 o[4];
  #pragma unroll
  for (int nt = 0; nt < 4; nt++) o[nt] = f32x4{0.f, 0.f, 0.f, 0.f};
  #pragma unroll
  for (int c = 0; c < 8; c++) {
    int kblk = c * 4 + quad;
    v8hf pa = *(const v8hf*)(KP + (wave * 16 + l16) * 256 + (kblk ^ fq) * 8);
    #pragma unroll
    for (int nt = 0; nt < 4; nt++) {
      v8hf vb = *(const v8hf*)(Vs + (nt * 16 + l16) * 256 + (kblk ^ fq) * 8);
      o[nt] = __builtin_amdgcn_mfma_f32_16x16x32_f16(pa, vb, o[nt], 0, 0, 0);
    }
  }

  _Float16* obase = ctx + (size_t)(b * 4096 + qt * 64 + wave * 16 + quad * 4) * 1024 + h * 64;
  #pragma unroll
  for (int nt = 0; nt < 4; nt++)
    #pragma unroll
    for (int r = 0; r < 4; r++)
      obase[(size_t)r * 1024 + nt * 16 + l16] = (_Float16)o[nt][r];
}

// ---------------------------------------------------------------------------
extern "C" void kernel_launch(void* const* d_in, const int* in_sizes, int n_in,
                              void* d_out, int out_size, void* d_ws, size_t ws_size,
                              hipStream_t stream)
{
  (void)in_sizes; (void)n_in; (void)out_size; (void)ws_size;

  const float* x   = (const float*)d_in[0];
  const float* Wq  = (const float*)d_in[1];
  const float* bq  = (const float*)d_in[2];
  const float* Wk  = (const float*)d_in[3];
  const float* bk  = (const float*)d_in[4];
  const float* Wv  = (const float*)d_in[5];
  const float* bv  = (const float*)d_in[6];
  const float* Wqt = (const float*)d_in[7];
  const float* bqt = (const float*)d_in[8];
  const float* Wo  = (const float*)d_in[9];
  const float* bo  = (const float*)d_in[10];

  char* ws = (char*)d_ws;
  _Float16* WtQKV = (_Float16*)(ws);                   // 3072x1024              6 MB
  _Float16* WtQT  = (_Float16*)(ws + (6ll  << 20));    // 1024x1024              2 MB
  _Float16* WtO   = (_Float16*)(ws + (8ll  << 20));    // 1024x1024              2 MB
  _Float16* qbuf  = (_Float16*)(ws + (10ll << 20));    // B,4096,1024           32 MB
  _Float16* kbuf  = (_Float16*)(ws + (42ll << 20));    // B,256,1024             2 MB
  _Float16* vtb   = (_Float16*)(ws + (44ll << 20));    // B*H,64,256             2 MB
  _Float16* ctxb  = (_Float16*)(ws + (46ll << 20));    // B,4096,1024           32 MB
  float* outp = (float*)d_out;

  TPArgs tpa;
  tpa.src[0] = Wq;  tpa.dst[0] = WtQKV;
  tpa.src[1] = Wk;  tpa.dst[1] = WtQKV + 1024 * 1024;
  tpa.src[2] = Wv;  tpa.dst[2] = WtQKV + 2 * 1024 * 1024;
  tpa.src[3] = Wqt; tpa.dst[3] = WtQT;
  tpa.src[4] = Wo;  tpa.dst[4] = WtO;
  transpose5_k<<<dim3(32, 32, 5), dim3(32, 8), 0, stream>>>(tpa);

  // anchors: M = B*256 = 1024, N = 3072 (q_a | k_a | v_a); A = x (fp32)
  gemm128<float, _Float16><<<dim3(24, 8), 256, 0, stream>>>(x, WtQKV, bq, bk, bv,
                                                            qbuf, kbuf, vtb, 256, 0, 1);
  // queries: M = B*3840 = 15360, N = 1024; A = x (fp32)
  gemm128<float, _Float16><<<dim3(8, 120), 256, 0, stream>>>(x, WtQT, bqt, nullptr, nullptr,
                                                             qbuf, nullptr, nullptr, 3840, 256, 0);
  // attention: B*H*(4096/64) = 4096 blocks
  attn_kernel<<<4096, 256, 0, stream>>>(qbuf, kbuf, vtb, ctxb);
  // out projection: M = B*4096 = 16384, N = 1024; A = ctx (fp16), fp32 out
  gemm128<_Float16, float><<<dim3(8, 128), 256, 0, stream>>>(ctxb, WtO, bo, nullptr, nullptr,
                                                             outp, nullptr, nullptr, 4096, 0, 0);
}

// Round 5
// 375.195 us; speedup vs baseline: 1.5302x; 1.5302x over previous
//
#include <hip/hip_runtime.h>
#include <stdint.h>
#include <stddef.h>

// AnchorAttention on MI355X (gfx950). FP32 I/O, fp16 MFMA internally.
// Round 5: round-3 proven DMA GEMM (no register staging - it spilled in R4)
//          + round-4's validated XCD-locality block remap (FETCH -60%).

typedef _Float16 v8hf __attribute__((ext_vector_type(8)));
typedef _Float16 h4   __attribute__((ext_vector_type(4)));
typedef float    f32x4 __attribute__((ext_vector_type(4)));

#define ATT_SCALE 0.125f   // 1/sqrt(64)
#define LOG2E     1.44269504088896340736f

__device__ __forceinline__ void async16(const void* g, void* l) {
  __builtin_amdgcn_global_load_lds(
      (const __attribute__((address_space(1))) void*)g,
      (__attribute__((address_space(3))) void*)l,
      16, 0, 0);
}

// ---------------------------------------------------------------------------
// fp32 -> fp16 elementwise convert (x), 4 elems/thread
// ---------------------------------------------------------------------------
__global__ __launch_bounds__(256) void cvt_kernel(const float* __restrict__ src,
                                                  _Float16* __restrict__ dst, int n) {
  int i = (blockIdx.x * 256 + threadIdx.x) * 4;
  if (i + 3 < n) {
    float4 v = *(const float4*)(src + i);
    h4 o; o[0] = (_Float16)v.x; o[1] = (_Float16)v.y; o[2] = (_Float16)v.z; o[3] = (_Float16)v.w;
    *(h4*)(dst + i) = o;
  }
}

// ---------------------------------------------------------------------------
// Fused transpose+convert for all 5 weight matrices (1024x1024 each):
//   dst[z][c*1024 + r] = (fp16)src[z][r*1024 + c]
// ---------------------------------------------------------------------------
struct TPArgs { const float* src[5]; _Float16* dst[5]; };

__global__ __launch_bounds__(256) void transpose5_k(TPArgs a) {
  __shared__ _Float16 t[32][33];
  const int z = blockIdx.z;
  const float* __restrict__ src = a.src[z];
  _Float16* __restrict__ dst = a.dst[z];
  const int bx = blockIdx.x * 32, by = blockIdx.y * 32;
  const int x = threadIdx.x;
  for (int yy = threadIdx.y; yy < 32; yy += 8)
    t[yy][x] = (_Float16)src[(size_t)(by + yy) * 1024 + bx + x];
  __syncthreads();
  for (int yy = threadIdx.y; yy < 32; yy += 8)
    dst[(size_t)(bx + yy) * 1024 + by + x] = t[x][yy];
}

// ---------------------------------------------------------------------------
// GEMM: C[m,n] = sum_k A[gRow(m),k] * Bt[n,k] + bias[n]
// 256 thr = 4 waves, 128x128 tile, BK=32, global_load_lds width-16 staging
// (round-3 proven body: 76 VGPR, no spills). XOR swizzle: blk ^= (row>>1)&3.
// XCD remap: lin%8 -> XCD; each XCD gets contiguous by-panels over all bx.
// ---------------------------------------------------------------------------
template <typename OutT>
__global__ __launch_bounds__(256) void gemm128(
    const _Float16* __restrict__ A, const _Float16* __restrict__ Bt,
    const float* __restrict__ bias0, const float* __restrict__ bias1,
    const float* __restrict__ bias2,
    OutT* __restrict__ out0, _Float16* __restrict__ out1, _Float16* __restrict__ out2,
    int rowsPerBatch, int rowStart, int mode)
{
  __shared__ __attribute__((aligned(16))) _Float16 As[128 * 32];
  __shared__ __attribute__((aligned(16))) _Float16 Bs[128 * 32];

  const int tid  = threadIdx.x;
  const int wave = tid >> 6, lane = tid & 63;
  const int quad = lane >> 4, l16 = lane & 15;
  const int wr = wave >> 1, wc = wave & 1;

  // XCD-locality remap (validated R4: FETCH 133->54 MB on out-proj)
  const int gx = gridDim.x;
  const int lin = blockIdx.y * gx + blockIdx.x;
  const int x8 = lin & 7, j = lin >> 3;
  const int bx = j % gx;
  const int by = x8 * (gridDim.y >> 3) + j / gx;

  const int c0 = wave * 2, c1 = c0 + 1;  // LDS chunks: 16 rows x 32 cols = 1 KB
  const int srow = lane >> 2;
  const int skol = (((lane & 3) ^ ((lane >> 3) & 3)) * 8);  // swizzled k-col

  auto gRowOf = [&](int m) -> int {
    int b = m / rowsPerBatch;
    int r = m - b * rowsPerBatch;
    return b * 4096 + rowStart + r;
  };

  const _Float16* aS0 = A  + (size_t)gRowOf(by * 128 + c0 * 16 + srow) * 1024 + skol;
  const _Float16* aS1 = A  + (size_t)gRowOf(by * 128 + c1 * 16 + srow) * 1024 + skol;
  const _Float16* bS0 = Bt + (size_t)(bx * 128 + c0 * 16 + srow) * 1024 + skol;
  const _Float16* bS1 = Bt + (size_t)(bx * 128 + c1 * 16 + srow) * 1024 + skol;
  _Float16* aD0 = As + c0 * 512;
  _Float16* aD1 = As + c1 * 512;
  _Float16* bD0 = Bs + c0 * 512;
  _Float16* bD1 = Bs + c1 * 512;

  // fragment-read swizzle: (row>>1)&3 = (l16>>1)&3 for 16-aligned row bases
  const int fblk = (quad ^ ((l16 >> 1) & 3)) * 8;

  f32x4 acc[4][4];
  #pragma unroll
  for (int i = 0; i < 4; i++)
    #pragma unroll
    for (int jj = 0; jj < 4; jj++)
      acc[i][jj] = f32x4{0.f, 0.f, 0.f, 0.f};

  for (int k0 = 0; k0 < 1024; k0 += 32) {
    __syncthreads();
    async16(aS0 + k0, aD0);
    async16(aS1 + k0, aD1);
    async16(bS0 + k0, bD0);
    async16(bS1 + k0, bD1);
    __syncthreads();

    v8hf af[4], bfr[4];
    #pragma unroll
    for (int mt = 0; mt < 4; mt++)
      af[mt] = *(const v8hf*)(As + (wr * 64 + mt * 16 + l16) * 32 + fblk);
    #pragma unroll
    for (int nt = 0; nt < 4; nt++)
      bfr[nt] = *(const v8hf*)(Bs + (wc * 64 + nt * 16 + l16) * 32 + fblk);
    #pragma unroll
    for (int mt = 0; mt < 4; mt++)
      #pragma unroll
      for (int nt = 0; nt < 4; nt++)
        acc[mt][nt] = __builtin_amdgcn_mfma_f32_16x16x32_f16(af[mt], bfr[nt], acc[mt][nt], 0, 0, 0);
  }

  // epilogue: C/D layout col=lane&15, row=quad*4+reg
  const int colBase = bx * 128 + wc * 64;
  const int rowBase = by * 128 + wr * 64;
  #pragma unroll
  for (int mt = 0; mt < 4; mt++) {
    #pragma unroll
    for (int r = 0; r < 4; r++) {
      int m = rowBase + mt * 16 + quad * 4 + r;
      int b = m / rowsPerBatch;
      int rr = m - b * rowsPerBatch;
      #pragma unroll
      for (int nt = 0; nt < 4; nt++) {
        int col = colBase + nt * 16 + l16;
        float v = acc[mt][nt][r];
        if (mode == 0) {
          v += bias0[col];
          out0[(size_t)(b * 4096 + rowStart + rr) * 1024 + col] = (OutT)v;
        } else {
          if (col < 1024) {
            v += bias0[col];
            out0[(size_t)(b * 4096 + rr) * 1024 + col] = (OutT)v;
          } else if (col < 2048) {
            int c2 = col - 1024;
            v += bias1[c2];
            out1[(size_t)(b * 256 + rr) * 1024 + c2] = (_Float16)v;
          } else {
            int c2 = col - 2048;  // vt[(b*16+h)*64+d][key]
            v += bias2[c2];
            out2[(size_t)((b * 16 + (c2 >> 6)) * 64 + (c2 & 63)) * 256 + rr] = (_Float16)v;
          }
        }
      }
    }
  }
}

// ---------------------------------------------------------------------------
// Fused attention: one block = (b, h, 64-query tile). K=256 anchors.
// LDS swizzle (Gray): 16B block blk at row r stored at blk ^ ((r^(r>>1))&7).
// ---------------------------------------------------------------------------
__global__ __launch_bounds__(256) void attn_kernel(
    const _Float16* __restrict__ q, const _Float16* __restrict__ k,
    const _Float16* __restrict__ vt, _Float16* __restrict__ ctx)
{
  __shared__ __attribute__((aligned(16))) _Float16 KP[256 * 64];  // K tile, then P
  __shared__ __attribute__((aligned(16))) _Float16 Vs[64 * 256];  // V^T (d x key)

  const int tid  = threadIdx.x;
  const int wave = tid >> 6, lane = tid & 63;
  const int quad = lane >> 4, l16 = lane & 15;
  const int bid = blockIdx.x;
  const int qt = bid & 63, h = (bid >> 6) & 15, b = bid >> 10;

  const int fq = (l16 ^ (l16 >> 1)) & 7;

  // stage K head tile (256x64 fp16 = 32 KB), swizzled source
  const _Float16* kbase = k + (size_t)b * 256 * 1024 + h * 64;
  {
    const int s = lane >> 3;
    const int p = lane & 7;
    #pragma unroll
    for (int i = 0; i < 8; i++) {
      int c = wave * 8 + i;
      int row = c * 8 + s;
      int f = (row ^ (row >> 1)) & 7;
      int dblk = p ^ f;
      async16(kbase + (size_t)row * 1024 + dblk * 8, KP + c * 512);
    }
  }

  // Q A-fragments straight from global
  const int qrow = qt * 64 + wave * 16 + l16;
  const _Float16* qbase = q + (size_t)(b * 4096 + qrow) * 1024 + h * 64 + quad * 8;
  v8hf a0 = *(const v8hf*)(qbase);
  v8hf a1 = *(const v8hf*)(qbase + 32);

  f32x4 s[16];
  #pragma unroll
  for (int t = 0; t < 16; t++) s[t] = f32x4{0.f, 0.f, 0.f, 0.f};

  __syncthreads();

  #pragma unroll
  for (int t = 0; t < 16; t++) {
    const _Float16* rbase = KP + (t * 16 + l16) * 64;
    int pb0 = (quad ^ fq) * 8;
    v8hf b0 = *(const v8hf*)(rbase + pb0);
    v8hf b1 = *(const v8hf*)(rbase + (pb0 ^ 32));
    s[t] = __builtin_amdgcn_mfma_f32_16x16x32_f16(a0, b0, s[t], 0, 0, 0);
    s[t] = __builtin_amdgcn_mfma_f32_16x16x32_f16(a1, b1, s[t], 0, 0, 0);
  }

  // softmax: lane (quad,l16) holds S[row=quad*4+r][key=t*16+l16]
  const float ce = ATT_SCALE * LOG2E;
  float inv[4];
  #pragma unroll
  for (int r = 0; r < 4; r++) {
    float m = s[0][r];
    #pragma unroll
    for (int t = 1; t < 16; t++) m = fmaxf(m, s[t][r]);
    m = fmaxf(m, __shfl_xor(m, 1));
    m = fmaxf(m, __shfl_xor(m, 2));
    m = fmaxf(m, __shfl_xor(m, 4));
    m = fmaxf(m, __shfl_xor(m, 8));
    float sum = 0.f;
    #pragma unroll
    for (int t = 0; t < 16; t++) {
      float e = exp2f((s[t][r] - m) * ce);
      s[t][r] = e;
      sum += e;
    }
    sum += __shfl_xor(sum, 1);
    sum += __shfl_xor(sum, 2);
    sum += __shfl_xor(sum, 4);
    sum += __shfl_xor(sum, 8);
    inv[r] = 1.0f / sum;
  }

  __syncthreads();  // all waves done reading K -> safe to overwrite with P

  // stage V^T head tile (64 d x 256 keys), swizzled source
  const _Float16* vbase = vt + (size_t)(b * 16 + h) * 16384;
  {
    const int p = lane & 31;
    #pragma unroll
    for (int i = 0; i < 8; i++) {
      int c = wave * 8 + i;
      int d = c * 2 + (lane >> 5);
      int f = (d ^ (d >> 1)) & 7;
      int kblk = p ^ f;
      async16(vbase + d * 256 + kblk * 8, Vs + c * 512);
    }
  }

  // write P into KP as P[64][256], swizzled
  #pragma unroll
  for (int r = 0; r < 4; r++) {
    int qr = wave * 16 + quad * 4 + r;
    int fp = (qr ^ (qr >> 1)) & 7;
    _Float16* prow = KP + qr * 256;
    #pragma unroll
    for (int t = 0; t < 16; t++) {
      int key = t * 16 + l16;
      prow[(((key >> 3) ^ fp) * 8) + (key & 7)] = (_Float16)(s[t][r] * inv[r]);
    }
  }

  __syncthreads();

  // ctx = P V
  f32x4 o[4];
  #pragma unroll
  for (int nt = 0; nt < 4; nt++) o[nt] = f32x4{0.f, 0.f, 0.f, 0.f};
  #pragma unroll
  for (int c = 0; c < 8; c++) {
    int kblk = c * 4 + quad;
    v8hf pa = *(const v8hf*)(KP + (wave * 16 + l16) * 256 + (kblk ^ fq) * 8);
    #pragma unroll
    for (int nt = 0; nt < 4; nt++) {
      v8hf vb = *(const v8hf*)(Vs + (nt * 16 + l16) * 256 + (kblk ^ fq) * 8);
      o[nt] = __builtin_amdgcn_mfma_f32_16x16x32_f16(pa, vb, o[nt], 0, 0, 0);
    }
  }

  _Float16* obase = ctx + (size_t)(b * 4096 + qt * 64 + wave * 16 + quad * 4) * 1024 + h * 64;
  #pragma unroll
  for (int nt = 0; nt < 4; nt++)
    #pragma unroll
    for (int r = 0; r < 4; r++)
      obase[(size_t)r * 1024 + nt * 16 + l16] = (_Float16)o[nt][r];
}

// ---------------------------------------------------------------------------
extern "C" void kernel_launch(void* const* d_in, const int* in_sizes, int n_in,
                              void* d_out, int out_size, void* d_ws, size_t ws_size,
                              hipStream_t stream)
{
  (void)in_sizes; (void)n_in; (void)out_size; (void)ws_size;

  const float* x   = (const float*)d_in[0];
  const float* Wq  = (const float*)d_in[1];
  const float* bq  = (const float*)d_in[2];
  const float* Wk  = (const float*)d_in[3];
  const float* bk  = (const float*)d_in[4];
  const float* Wv  = (const float*)d_in[5];
  const float* bv  = (const float*)d_in[6];
  const float* Wqt = (const float*)d_in[7];
  const float* bqt = (const float*)d_in[8];
  const float* Wo  = (const float*)d_in[9];
  const float* bo  = (const float*)d_in[10];

  char* ws = (char*)d_ws;
  _Float16* xh    = (_Float16*)(ws);                   // B*4096*1024 fp16      32 MB
  _Float16* WtQKV = (_Float16*)(ws + (32ll << 20));    // 3072x1024              6 MB
  _Float16* WtQT  = (_Float16*)(ws + (38ll << 20));    // 1024x1024              2 MB
  _Float16* WtO   = (_Float16*)(ws + (40ll << 20));    // 1024x1024              2 MB
  _Float16* qbuf  = (_Float16*)(ws + (42ll << 20));    // B,4096,1024           32 MB
  _Float16* kbuf  = (_Float16*)(ws + (74ll << 20));    // B,256,1024             2 MB
  _Float16* vtb   = (_Float16*)(ws + (76ll << 20));    // B*H,64,256             2 MB
  _Float16* ctxb  = (_Float16*)(ws + (78ll << 20));    // B,4096,1024           32 MB
  float* outp = (float*)d_out;

  const int nx = 4 * 4096 * 1024;
  cvt_kernel<<<nx / 1024, 256, 0, stream>>>(x, xh, nx);

  TPArgs tpa;
  tpa.src[0] = Wq;  tpa.dst[0] = WtQKV;
  tpa.src[1] = Wk;  tpa.dst[1] = WtQKV + 1024 * 1024;
  tpa.src[2] = Wv;  tpa.dst[2] = WtQKV + 2 * 1024 * 1024;
  tpa.src[3] = Wqt; tpa.dst[3] = WtQT;
  tpa.src[4] = Wo;  tpa.dst[4] = WtO;
  transpose5_k<<<dim3(32, 32, 5), dim3(32, 8), 0, stream>>>(tpa);

  // anchors: M = B*256 = 1024, N = 3072  (q_a | k_a | v_a)
  gemm128<_Float16><<<dim3(24, 8), 256, 0, stream>>>(xh, WtQKV, bq, bk, bv,
                                                     qbuf, kbuf, vtb, 256, 0, 1);
  // queries: M = B*3840 = 15360, N = 1024
  gemm128<_Float16><<<dim3(8, 120), 256, 0, stream>>>(xh, WtQT, bqt, nullptr, nullptr,
                                                      qbuf, nullptr, nullptr, 3840, 256, 0);
  // attention: B*H*(4096/64) = 4096 blocks
  attn_kernel<<<4096, 256, 0, stream>>>(qbuf, kbuf, vtb, ctxb);
  // out projection: M = B*4096 = 16384, N = 1024, fp32 out
  gemm128<float><<<dim3(8, 128), 256, 0, stream>>>(ctxb, WtO, bo, nullptr, nullptr,
                                                   outp, nullptr, nullptr, 4096, 0, 0);
}